// Round 8
// baseline (1097.376 us; speedup 1.0000x reference)
//
#include <hip/hip_runtime.h>

// ---------------------------------------------------------------------------
// BertAlibiUnpadSelfAttention on MI355X.
// MEASUREMENT ROUND: real path byte-identical to R7 (best, 593.2us).
// Four probe kernels appended (no output, asm keep-alives, 64 steps = 2
// k-sweeps so bias L3-thrashes honestly):
//   P1 staging skeleton | P2 +bias loads | P3 +QKT/softmax/Pstore | P4 full.
// Marginals locate the attn pole. P4 ~ 2x real attn (sanity anchor).
// ---------------------------------------------------------------------------

typedef __attribute__((ext_vector_type(8))) short short8;
typedef __attribute__((ext_vector_type(4))) float floatx4;
typedef unsigned short u16;
typedef unsigned int u32;

#define LOG2E 1.4426950408889634f

__device__ __forceinline__ u16 f2bf(float f) {
  u32 u = __float_as_uint(f);
  u += 0x7FFFu + ((u >> 16) & 1u);   // round-to-nearest-even
  return (u16)(u >> 16);
}

typedef const __attribute__((address_space(1))) u32* gp_t;
typedef __attribute__((address_space(3))) u32* lp_t;
__device__ __forceinline__ void async_cp16(const void* g, void* l) {
  __builtin_amdgcn_global_load_lds((gp_t)g, (lp_t)l, 16, 0, 0);
}

// ------------------------------- K1: pack ----------------------------------
__global__ __launch_bounds__(256) void pack_kernel(
    const float* __restrict__ A, const float* __restrict__ W,
    u16* __restrict__ Abf, u16* __restrict__ Wbf) {
  unsigned u = blockIdx.x * 256u + threadIdx.x;  // 1,228,800 float4 units
  const unsigned nA = 786432u;                   // 4096*768/4
  float4 v;
  u16* dst;
  if (u < nA) { v = ((const float4*)A)[u]; dst = Abf + u * 4; }
  else        { unsigned q = u - nA; v = ((const float4*)W)[q]; dst = Wbf + q * 4; }
  ushort4 o;
  o.x = f2bf(v.x); o.y = f2bf(v.y); o.z = f2bf(v.z); o.w = f2bf(v.w);
  *(ushort4*)dst = o;
}

// ------------------------------- K2: qkv gemm ------------------------------
__global__ __launch_bounds__(256, 3) void qkv_gemm(
    const u16* __restrict__ Abf, const u16* __restrict__ Wbf,
    const float* __restrict__ bq,
    u16* __restrict__ Qb, u16* __restrict__ Kb, u16* __restrict__ Vb) {
  __shared__ __align__(16) char smem[32768];
  char* As0 = smem;
  char* Bs0 = smem + 8192;
  char* As1 = smem + 16384;
  char* Bs1 = smem + 24576;
  const unsigned t = threadIdx.x;
  unsigned orig = blockIdx.y * 18u + blockIdx.x;
  unsigned wg = (orig & 7u) * 72u + (orig >> 3);
  const unsigned nblk = wg % 18u, mblk = wg / 18u;
  const unsigned w = t >> 6, l = t & 63, quad = l >> 4, c = l & 15;
  const unsigned wm = (w >> 1) * 64, wn = (w & 1) * 64;

  floatx4 acc[4][4] = {};

  const unsigned b0 = t, b1 = t + 256u;
  const unsigned r0 = b0 >> 2, ch0 = (b0 & 3u) ^ (r0 & 3u);
  const unsigned r1 = b1 >> 2, ch1 = (b1 & 3u) ^ (r1 & 3u);
  const char* gA0 = (const char*)Abf + (size_t)((mblk * 128 + r0) * 768) * 2 + ch0 * 16;
  const char* gA1 = (const char*)Abf + (size_t)((mblk * 128 + r1) * 768) * 2 + ch1 * 16;
  const char* gB0 = (const char*)Wbf + (size_t)((nblk * 128 + r0) * 768) * 2 + ch0 * 16;
  const char* gB1 = (const char*)Wbf + (size_t)((nblk * 128 + r1) * 768) * 2 + ch1 * 16;

  async_cp16(gA0, As0 + b0 * 16);
  async_cp16(gA1, As0 + b1 * 16);
  async_cp16(gB0, Bs0 + b0 * 16);
  async_cp16(gB1, Bs0 + b1 * 16);
  __syncthreads();

  for (unsigned kt = 0; kt < 24; ++kt) {
    char* Ac = (kt & 1u) ? As1 : As0;
    char* Bc = (kt & 1u) ? Bs1 : Bs0;
    if (kt + 1 < 24) {
      char* An = (kt & 1u) ? As0 : As1;
      char* Bn = (kt & 1u) ? Bs0 : Bs1;
      async_cp16(gA0 + (kt + 1) * 64, An + b0 * 16);
      async_cp16(gA1 + (kt + 1) * 64, An + b1 * 16);
      async_cp16(gB0 + (kt + 1) * 64, Bn + b0 * 16);
      async_cp16(gB1 + (kt + 1) * 64, Bn + b1 * 16);
    }
    short8 af[4], bf[4];
#pragma unroll
    for (int mt = 0; mt < 4; ++mt) {
      unsigned row = wm + mt * 16 + c;
      af[mt] = *(const short8*)(Ac + row * 64 + 16 * (quad ^ (row & 3u)));
    }
#pragma unroll
    for (int nt = 0; nt < 4; ++nt) {
      unsigned row = wn + nt * 16 + c;
      bf[nt] = *(const short8*)(Bc + row * 64 + 16 * (quad ^ (row & 3u)));
    }
#pragma unroll
    for (int mt = 0; mt < 4; ++mt)
#pragma unroll
      for (int nt = 0; nt < 4; ++nt)
        acc[mt][nt] = __builtin_amdgcn_mfma_f32_16x16x32_bf16(af[mt], bf[nt], acc[mt][nt], 0, 0, 0);
    __syncthreads();
  }

  float bqv[4];
#pragma unroll
  for (int nt = 0; nt < 4; ++nt) bqv[nt] = bq[nblk * 128 + wn + nt * 16 + c];
#pragma unroll
  for (int mt = 0; mt < 4; ++mt) {
#pragma unroll
    for (int r = 0; r < 4; ++r) {
      unsigned m = mblk * 128 + wm + mt * 16 + quad * 4 + r;
      unsigned bb = m >> 11, s = m & 2047u;
#pragma unroll
      for (int nt = 0; nt < 4; ++nt) {
        float val = acc[mt][nt][r] + bqv[nt];
        unsigned n = nblk * 128 + wn + nt * 16 + c;
        u16 bv = f2bf(val);
        if (n < 768u) {
          unsigned h = n >> 6, d = n & 63u;
          Qb[(((bb * 12 + h) * 2048 + s) << 6) + d] = bv;
        } else if (n < 1536u) {
          unsigned n2 = n - 768u, h = n2 >> 6, d = n2 & 63u;
          Kb[(((bb * 12 + h) * 2048 + s) << 6) + d] = bv;
        } else {
          unsigned n2 = n - 1536u, h = n2 >> 6, d = n2 & 63u;
          Vb[(((bb * 12 + h) << 6) + d) * 2048 + s] = bv;
        }
      }
    }
  }
}

// ------------------------------- K3: attention (R7, unchanged) -------------
__global__ __launch_bounds__(256, 3) void attn_kernel(
    const u16* __restrict__ Qb, const u16* __restrict__ Kb,
    const u16* __restrict__ Vb, const float* __restrict__ bias,
    float* __restrict__ out) {
  __shared__ __align__(16) char smem[40960];
  char* Ks0 = smem;
  char* Ks1 = smem + 8192;
  char* Vs0 = smem + 16384;
  char* Vs1 = smem + 24576;
  char* Ps  = smem + 32768;
  const unsigned t = threadIdx.x;
  unsigned wgid = (blockIdx.x & 7u) * 96u + (blockIdx.x >> 3);
  const unsigned bh = wgid >> 5, qt = wgid & 31u;
  const unsigned q0 = qt * 64;
  const unsigned w = t >> 6, l = t & 63, quad = l >> 4, c = l & 15;
  const unsigned pb = w * 2048u;

  const unsigned b0 = t, b1 = t + 256u;
  const unsigned r0 = b0 >> 3, ch0 = (b0 & 7u) ^ (r0 & 7u);
  const unsigned r1 = b1 >> 3, ch1 = (b1 & 7u) ^ (r1 & 7u);

  const char* gK0 = (const char*)Kb + (size_t)(bh * 2048 + r0) * 128 + ch0 * 16;
  const char* gK1 = (const char*)Kb + (size_t)(bh * 2048 + r1) * 128 + ch1 * 16;
  const char* gV0 = (const char*)Vb + (size_t)(bh * 64 + r0) * 4096 + ch0 * 16;
  const char* gV1 = (const char*)Vb + (size_t)(bh * 64 + r1) * 4096 + ch1 * 16;
  const float* bias_base = bias + (size_t)(bh * 2048 + q0 + w * 16 + quad * 4) * 2048 + c;

  async_cp16(gK0, Ks0 + b0 * 16);
  async_cp16(gK1, Ks0 + b1 * 16);
  async_cp16(gV0, Vs0 + b0 * 16);
  async_cp16(gV1, Vs0 + b1 * 16);
  short8 aq[2];
  {
    const u16* qrow = Qb + (size_t)(bh * 2048 + q0 + w * 16 + c) * 64 + quad * 8;
    aq[0] = *(const short8*)(qrow);
    aq[1] = *(const short8*)(qrow + 32);
  }
  float bvA[4][4], bvB[4][4];
#pragma unroll
  for (int tt = 0; tt < 4; ++tt)
#pragma unroll
    for (int r = 0; r < 4; ++r)
      bvA[tt][r] = bias_base[(size_t)r * 2048 + tt * 16] * LOG2E;
  __syncthreads();

  float lsum[4] = {0.f, 0.f, 0.f, 0.f};
  floatx4 oacc[4] = {};

  for (unsigned i = 0; i < 32; ++i) {
    const unsigned k0 = i * 64u;
    const char* Kc = (i & 1u) ? Ks1 : Ks0;
    const char* Vc = (i & 1u) ? Vs1 : Vs0;

    if (i + 1 < 32) {
      char* Kn = (i & 1u) ? Ks0 : Ks1;
      char* Vn = (i & 1u) ? Vs0 : Vs1;
      async_cp16(gK0 + (size_t)(k0 + 64) * 128, Kn + b0 * 16);
      async_cp16(gK1 + (size_t)(k0 + 64) * 128, Kn + b1 * 16);
      async_cp16(gV0 + (size_t)(k0 + 64) * 2, Vn + b0 * 16);
      async_cp16(gV1 + (size_t)(k0 + 64) * 2, Vn + b1 * 16);
#pragma unroll
      for (int tt = 0; tt < 4; ++tt)
#pragma unroll
        for (int r = 0; r < 4; ++r)
          bvB[tt][r] = bias_base[(size_t)r * 2048 + (k0 + 64) + tt * 16] * LOG2E;
    }

    floatx4 s4[4] = {};
    __builtin_amdgcn_s_setprio(1);
#pragma unroll
    for (int ds = 0; ds < 2; ++ds)
#pragma unroll
      for (int tt = 0; tt < 4; ++tt) {
        unsigned row = tt * 16 + c;
        short8 kf = *(const short8*)(Kc + row * 128 + 16 * (((unsigned)quad + 4u * ds) ^ (c & 7u)));
        s4[tt] = __builtin_amdgcn_mfma_f32_16x16x32_bf16(aq[ds], kf, s4[tt], 0, 0, 0);
      }
    __builtin_amdgcn_s_setprio(0);

#pragma unroll
    for (int tt = 0; tt < 4; ++tt)
#pragma unroll
      for (int r = 0; r < 4; ++r)
        s4[tt][r] = __builtin_amdgcn_exp2f(fmaf(s4[tt][r], (LOG2E / 8.0f), bvA[tt][r]));
#pragma unroll
    for (int r = 0; r < 4; ++r)
      lsum[r] += (s4[0][r] + s4[1][r]) + (s4[2][r] + s4[3][r]);

#pragma unroll
    for (int tt = 0; tt < 4; ++tt)
#pragma unroll
      for (int r = 0; r < 4; ++r) {
        unsigned qq = quad * 4 + r;
        unsigned off = pb + qq * 128 + 16 * (((unsigned)(2 * tt) + (c >> 3)) ^ (qq & 7u)) + 2 * (c & 7u);
        *(u16*)(Ps + off) = f2bf(s4[tt][r]);
      }
    asm volatile("s_waitcnt lgkmcnt(0)" ::: "memory");

    __builtin_amdgcn_s_setprio(1);
#pragma unroll
    for (int js = 0; js < 2; ++js) {
      short8 pf = *(const short8*)(Ps + pb + (l & 15) * 128 +
                                   16 * (((unsigned)quad + 4u * js) ^ ((l & 15) & 7u)));
#pragma unroll
      for (int dt = 0; dt < 4; ++dt) {
        unsigned row = dt * 16 + c;
        short8 vf = *(const short8*)(Vc + row * 128 + 16 * (((unsigned)quad + 4u * js) ^ (c & 7u)));
        oacc[dt] = __builtin_amdgcn_mfma_f32_16x16x32_bf16(pf, vf, oacc[dt], 0, 0, 0);
      }
    }
    __builtin_amdgcn_s_setprio(0);

    __syncthreads();

    if (i + 1 < 32) {
#pragma unroll
      for (int tt = 0; tt < 4; ++tt)
#pragma unroll
        for (int r = 0; r < 4; ++r)
          bvA[tt][r] = bvB[tt][r];
    }
  }

#pragma unroll
  for (int r = 0; r < 4; ++r) {
    float rs = lsum[r];
    rs += __shfl_xor(rs, 1);
    rs += __shfl_xor(rs, 2);
    rs += __shfl_xor(rs, 4);
    rs += __shfl_xor(rs, 8);
    lsum[r] = rs;
  }
  unsigned b_ = bh / 12u, h = bh % 12u;
#pragma unroll
  for (int r = 0; r < 4; ++r) {
    float li = 1.0f / lsum[r];
    unsigned qg = q0 + w * 16 + quad * 4 + r;
    float* op = out + (size_t)(b_ * 2048 + qg) * 768 + h * 64 + c;
#pragma unroll
    for (int dt = 0; dt < 4; ++dt) op[dt * 16] = oacc[dt][r] * li;
  }
}

// ------------------------------- probes ------------------------------------
// 64 steps (2 k-sweeps, key index wraps). MODE 1: staging skeleton.
// MODE 2: +bias reg loads. MODE 3: +QKT+softmax+Pstore. MODE 4: full body.
// No global output; results folded into fsum and kept alive via asm.
template <int MODE>
__global__ __launch_bounds__(256, 3) void probe_kernel(
    const u16* __restrict__ Qb, const u16* __restrict__ Kb,
    const u16* __restrict__ Vb, const float* __restrict__ bias) {
  __shared__ __align__(16) char smem[40960];
  char* Ks0 = smem;
  char* Ks1 = smem + 8192;
  char* Vs0 = smem + 16384;
  char* Vs1 = smem + 24576;
  char* Ps  = smem + 32768;
  const unsigned t = threadIdx.x;
  unsigned wgid = (blockIdx.x & 7u) * 96u + (blockIdx.x >> 3);
  const unsigned bh = wgid >> 5, qt = wgid & 31u;
  const unsigned q0 = qt * 64;
  const unsigned w = t >> 6, l = t & 63, quad = l >> 4, c = l & 15;
  const unsigned pb = w * 2048u;

  const unsigned b0 = t, b1 = t + 256u;
  const unsigned r0 = b0 >> 3, ch0 = (b0 & 7u) ^ (r0 & 7u);
  const unsigned r1 = b1 >> 3, ch1 = (b1 & 7u) ^ (r1 & 7u);

  const char* gK0 = (const char*)Kb + (size_t)(bh * 2048 + r0) * 128 + ch0 * 16;
  const char* gK1 = (const char*)Kb + (size_t)(bh * 2048 + r1) * 128 + ch1 * 16;
  const char* gV0 = (const char*)Vb + (size_t)(bh * 64 + r0) * 4096 + ch0 * 16;
  const char* gV1 = (const char*)Vb + (size_t)(bh * 64 + r1) * 4096 + ch1 * 16;
  const float* bias_base = bias + (size_t)(bh * 2048 + q0 + w * 16 + quad * 4) * 2048 + c;

  async_cp16(gK0, Ks0 + b0 * 16);
  async_cp16(gK1, Ks0 + b1 * 16);
  async_cp16(gV0, Vs0 + b0 * 16);
  async_cp16(gV1, Vs0 + b1 * 16);
  short8 aq[2] = {};
  if (MODE >= 3) {
    const u16* qrow = Qb + (size_t)(bh * 2048 + q0 + w * 16 + c) * 64 + quad * 8;
    aq[0] = *(const short8*)(qrow);
    aq[1] = *(const short8*)(qrow + 32);
  }
  float bvA[4][4] = {}, bvB[4][4] = {};
  if (MODE >= 2) {
#pragma unroll
    for (int tt = 0; tt < 4; ++tt)
#pragma unroll
      for (int r = 0; r < 4; ++r)
        bvA[tt][r] = bias_base[(size_t)r * 2048 + tt * 16] * LOG2E;
  }
  __syncthreads();

  float fsum = 0.f;
  float lsum[4] = {0.f, 0.f, 0.f, 0.f};
  floatx4 oacc[4] = {};

  for (unsigned i = 0; i < 64; ++i) {
    const char* Kc = (i & 1u) ? Ks1 : Ks0;
    const char* Vc = (i & 1u) ? Vs1 : Vs0;
    const unsigned kn = ((i + 1) & 31u) * 64u;  // next step's key start (wraps)

    if (i + 1 < 64) {
      char* Kn = (i & 1u) ? Ks0 : Ks1;
      char* Vn = (i & 1u) ? Vs0 : Vs1;
      async_cp16(gK0 + (size_t)kn * 128, Kn + b0 * 16);
      async_cp16(gK1 + (size_t)kn * 128, Kn + b1 * 16);
      async_cp16(gV0 + (size_t)kn * 2, Vn + b0 * 16);
      async_cp16(gV1 + (size_t)kn * 2, Vn + b1 * 16);
      if (MODE >= 2) {
#pragma unroll
        for (int tt = 0; tt < 4; ++tt)
#pragma unroll
          for (int r = 0; r < 4; ++r)
            bvB[tt][r] = bias_base[(size_t)r * 2048 + kn + tt * 16] * LOG2E;
      }
    }

    if (MODE >= 3) {
      floatx4 s4[4] = {};
      __builtin_amdgcn_s_setprio(1);
#pragma unroll
      for (int ds = 0; ds < 2; ++ds)
#pragma unroll
        for (int tt = 0; tt < 4; ++tt) {
          unsigned row = tt * 16 + c;
          short8 kf = *(const short8*)(Kc + row * 128 + 16 * (((unsigned)quad + 4u * ds) ^ (c & 7u)));
          s4[tt] = __builtin_amdgcn_mfma_f32_16x16x32_bf16(aq[ds], kf, s4[tt], 0, 0, 0);
        }
      __builtin_amdgcn_s_setprio(0);
#pragma unroll
      for (int tt = 0; tt < 4; ++tt)
#pragma unroll
        for (int r = 0; r < 4; ++r)
          s4[tt][r] = __builtin_amdgcn_exp2f(fmaf(s4[tt][r], (LOG2E / 8.0f), bvA[tt][r]));
#pragma unroll
      for (int r = 0; r < 4; ++r)
        lsum[r] += (s4[0][r] + s4[1][r]) + (s4[2][r] + s4[3][r]);
#pragma unroll
      for (int tt = 0; tt < 4; ++tt)
#pragma unroll
        for (int r = 0; r < 4; ++r) {
          unsigned qq = quad * 4 + r;
          unsigned off = pb + qq * 128 + 16 * (((unsigned)(2 * tt) + (c >> 3)) ^ (qq & 7u)) + 2 * (c & 7u);
          *(u16*)(Ps + off) = f2bf(s4[tt][r]);
        }
      asm volatile("s_waitcnt lgkmcnt(0)" ::: "memory");

      if (MODE >= 4) {
        __builtin_amdgcn_s_setprio(1);
#pragma unroll
        for (int js = 0; js < 2; ++js) {
          short8 pf = *(const short8*)(Ps + pb + (l & 15) * 128 +
                                       16 * (((unsigned)quad + 4u * js) ^ ((l & 15) & 7u)));
#pragma unroll
          for (int dt = 0; dt < 4; ++dt) {
            unsigned row = dt * 16 + c;
            short8 vf = *(const short8*)(Vc + row * 128 + 16 * (((unsigned)quad + 4u * js) ^ (c & 7u)));
            oacc[dt] = __builtin_amdgcn_mfma_f32_16x16x32_bf16(pf, vf, oacc[dt], 0, 0, 0);
          }
        }
        __builtin_amdgcn_s_setprio(0);
      }
    } else if (MODE == 2) {
      // consume bias cheaply so the loads are live
#pragma unroll
      for (int tt = 0; tt < 4; ++tt)
#pragma unroll
        for (int r = 0; r < 4; ++r) fsum += bvA[tt][r];
    }

    __syncthreads();

    if (i + 1 < 64 && MODE >= 2) {
#pragma unroll
      for (int tt = 0; tt < 4; ++tt)
#pragma unroll
        for (int r = 0; r < 4; ++r)
          bvA[tt][r] = bvB[tt][r];
    }
  }

  // keep-alives (no global output)
  if (MODE >= 3) {
#pragma unroll
    for (int r = 0; r < 4; ++r) fsum += lsum[r];
  }
  if (MODE >= 4) {
#pragma unroll
    for (int dt = 0; dt < 4; ++dt)
#pragma unroll
      for (int r = 0; r < 4; ++r) fsum += oacc[dt][r];
  }
  asm volatile("" :: "v"(fsum));
}

// ------------------------------- launch ------------------------------------
extern "C" void kernel_launch(void* const* d_in, const int* in_sizes, int n_in,
                              void* d_out, int out_size, void* d_ws, size_t ws_size,
                              hipStream_t stream) {
  const float* hidden = (const float*)d_in[0];   // 4096 x 768
  const float* Wqkv_w = (const float*)d_in[1];   // 2304 x 768
  const float* Wqkv_b = (const float*)d_in[2];   // 2304
  const float* bias   = (const float*)d_in[3];   // 2 x 12 x 2048 x 2048
  float* out = (float*)d_out;

  char* ws = (char*)d_ws;
  u16* Abf = (u16*)(ws);                 //  6,291,456 B
  u16* Wbf = (u16*)(ws + 6291456);       //  3,538,944 B
  u16* Qb  = (u16*)(ws + 9830400);       //  6,291,456 B
  u16* Kb  = (u16*)(ws + 16121856);      //  6,291,456 B
  u16* Vb  = (u16*)(ws + 22413312);      //  6,291,456 B  (total ~27.4 MB)

  pack_kernel<<<4800, 256, 0, stream>>>(hidden, Wqkv_w, Abf, Wbf);
  qkv_gemm<<<dim3(18, 32), 256, 0, stream>>>(Abf, Wbf, Wqkv_b, Qb, Kb, Vb);
  attn_kernel<<<768, 256, 0, stream>>>(Qb, Kb, Vb, bias, out);
  // ---- measurement probes (no output; located via rocprof top-5) ----
  probe_kernel<1><<<768, 256, 0, stream>>>(Qb, Kb, Vb, bias);
  probe_kernel<2><<<768, 256, 0, stream>>>(Qb, Kb, Vb, bias);
  probe_kernel<3><<<768, 256, 0, stream>>>(Qb, Kb, Vb, bias);
  probe_kernel<4><<<768, 256, 0, stream>>>(Qb, Kb, Vb, bias);
}

// Round 10
// 1093.438 us; speedup vs baseline: 1.0036x; 1.0036x over previous
//
#include <hip/hip_runtime.h>

// ---------------------------------------------------------------------------
// BertAlibiUnpadSelfAttention on MI355X.
// Real path = R7 exactly (best passing: 593.2us, absmax 2.9e-3).
// MEASUREMENT: two 128-step probes (4 k-sweeps) appended, sized to crack the
// fill-dominated rocprof top-5 and expose the attn body's own counters:
//   PF (BIAS=1): exact R7 body.   PN (BIAS=0): bias loads removed.
// PF-PN isolates bias cost; PN counters classify the rest (VALU vs latency).
// ---------------------------------------------------------------------------

typedef __attribute__((ext_vector_type(8))) short short8;
typedef __attribute__((ext_vector_type(4))) float floatx4;
typedef unsigned short u16;
typedef unsigned int u32;

#define LOG2E 1.4426950408889634f

__device__ __forceinline__ u16 f2bf(float f) {
  u32 u = __float_as_uint(f);
  u += 0x7FFFu + ((u >> 16) & 1u);   // round-to-nearest-even
  return (u16)(u >> 16);
}

typedef const __attribute__((address_space(1))) u32* gp_t;
typedef __attribute__((address_space(3))) u32* lp_t;
__device__ __forceinline__ void async_cp16(const void* g, void* l) {
  __builtin_amdgcn_global_load_lds((gp_t)g, (lp_t)l, 16, 0, 0);
}

// ------------------------------- K1: pack ----------------------------------
__global__ __launch_bounds__(256) void pack_kernel(
    const float* __restrict__ A, const float* __restrict__ W,
    u16* __restrict__ Abf, u16* __restrict__ Wbf) {
  unsigned u = blockIdx.x * 256u + threadIdx.x;  // 1,228,800 float4 units
  const unsigned nA = 786432u;                   // 4096*768/4
  float4 v;
  u16* dst;
  if (u < nA) { v = ((const float4*)A)[u]; dst = Abf + u * 4; }
  else        { unsigned q = u - nA; v = ((const float4*)W)[q]; dst = Wbf + q * 4; }
  ushort4 o;
  o.x = f2bf(v.x); o.y = f2bf(v.y); o.z = f2bf(v.z); o.w = f2bf(v.w);
  *(ushort4*)dst = o;
}

// ------------------------------- K2: qkv gemm ------------------------------
__global__ __launch_bounds__(256, 3) void qkv_gemm(
    const u16* __restrict__ Abf, const u16* __restrict__ Wbf,
    const float* __restrict__ bq,
    u16* __restrict__ Qb, u16* __restrict__ Kb, u16* __restrict__ Vb) {
  __shared__ __align__(16) char smem[32768];
  char* As0 = smem;
  char* Bs0 = smem + 8192;
  char* As1 = smem + 16384;
  char* Bs1 = smem + 24576;
  const unsigned t = threadIdx.x;
  unsigned orig = blockIdx.y * 18u + blockIdx.x;
  unsigned wg = (orig & 7u) * 72u + (orig >> 3);
  const unsigned nblk = wg % 18u, mblk = wg / 18u;
  const unsigned w = t >> 6, l = t & 63, quad = l >> 4, c = l & 15;
  const unsigned wm = (w >> 1) * 64, wn = (w & 1) * 64;

  floatx4 acc[4][4] = {};

  const unsigned b0 = t, b1 = t + 256u;
  const unsigned r0 = b0 >> 2, ch0 = (b0 & 3u) ^ (r0 & 3u);
  const unsigned r1 = b1 >> 2, ch1 = (b1 & 3u) ^ (r1 & 3u);
  const char* gA0 = (const char*)Abf + (size_t)((mblk * 128 + r0) * 768) * 2 + ch0 * 16;
  const char* gA1 = (const char*)Abf + (size_t)((mblk * 128 + r1) * 768) * 2 + ch1 * 16;
  const char* gB0 = (const char*)Wbf + (size_t)((nblk * 128 + r0) * 768) * 2 + ch0 * 16;
  const char* gB1 = (const char*)Wbf + (size_t)((nblk * 128 + r1) * 768) * 2 + ch1 * 16;

  async_cp16(gA0, As0 + b0 * 16);
  async_cp16(gA1, As0 + b1 * 16);
  async_cp16(gB0, Bs0 + b0 * 16);
  async_cp16(gB1, Bs0 + b1 * 16);
  __syncthreads();

  for (unsigned kt = 0; kt < 24; ++kt) {
    char* Ac = (kt & 1u) ? As1 : As0;
    char* Bc = (kt & 1u) ? Bs1 : Bs0;
    if (kt + 1 < 24) {
      char* An = (kt & 1u) ? As0 : As1;
      char* Bn = (kt & 1u) ? Bs0 : Bs1;
      async_cp16(gA0 + (kt + 1) * 64, An + b0 * 16);
      async_cp16(gA1 + (kt + 1) * 64, An + b1 * 16);
      async_cp16(gB0 + (kt + 1) * 64, Bn + b0 * 16);
      async_cp16(gB1 + (kt + 1) * 64, Bn + b1 * 16);
    }
    short8 af[4], bf[4];
#pragma unroll
    for (int mt = 0; mt < 4; ++mt) {
      unsigned row = wm + mt * 16 + c;
      af[mt] = *(const short8*)(Ac + row * 64 + 16 * (quad ^ (row & 3u)));
    }
#pragma unroll
    for (int nt = 0; nt < 4; ++nt) {
      unsigned row = wn + nt * 16 + c;
      bf[nt] = *(const short8*)(Bc + row * 64 + 16 * (quad ^ (row & 3u)));
    }
#pragma unroll
    for (int mt = 0; mt < 4; ++mt)
#pragma unroll
      for (int nt = 0; nt < 4; ++nt)
        acc[mt][nt] = __builtin_amdgcn_mfma_f32_16x16x32_bf16(af[mt], bf[nt], acc[mt][nt], 0, 0, 0);
    __syncthreads();
  }

  float bqv[4];
#pragma unroll
  for (int nt = 0; nt < 4; ++nt) bqv[nt] = bq[nblk * 128 + wn + nt * 16 + c];
#pragma unroll
  for (int mt = 0; mt < 4; ++mt) {
#pragma unroll
    for (int r = 0; r < 4; ++r) {
      unsigned m = mblk * 128 + wm + mt * 16 + quad * 4 + r;
      unsigned bb = m >> 11, s = m & 2047u;
#pragma unroll
      for (int nt = 0; nt < 4; ++nt) {
        float val = acc[mt][nt][r] + bqv[nt];
        unsigned n = nblk * 128 + wn + nt * 16 + c;
        u16 bv = f2bf(val);
        if (n < 768u) {
          unsigned h = n >> 6, d = n & 63u;
          Qb[(((bb * 12 + h) * 2048 + s) << 6) + d] = bv;
        } else if (n < 1536u) {
          unsigned n2 = n - 768u, h = n2 >> 6, d = n2 & 63u;
          Kb[(((bb * 12 + h) * 2048 + s) << 6) + d] = bv;
        } else {
          unsigned n2 = n - 1536u, h = n2 >> 6, d = n2 & 63u;
          Vb[(((bb * 12 + h) << 6) + d) * 2048 + s] = bv;
        }
      }
    }
  }
}

// ------------------------------- K3: attention (R7, verbatim) --------------
__global__ __launch_bounds__(256, 3) void attn_kernel(
    const u16* __restrict__ Qb, const u16* __restrict__ Kb,
    const u16* __restrict__ Vb, const float* __restrict__ bias,
    float* __restrict__ out) {
  __shared__ __align__(16) char smem[40960];
  char* Ks0 = smem;
  char* Ks1 = smem + 8192;
  char* Vs0 = smem + 16384;
  char* Vs1 = smem + 24576;
  char* Ps  = smem + 32768;
  const unsigned t = threadIdx.x;
  unsigned wgid = (blockIdx.x & 7u) * 96u + (blockIdx.x >> 3);
  const unsigned bh = wgid >> 5, qt = wgid & 31u;
  const unsigned q0 = qt * 64;
  const unsigned w = t >> 6, l = t & 63, quad = l >> 4, c = l & 15;
  const unsigned pb = w * 2048u;

  const unsigned b0 = t, b1 = t + 256u;
  const unsigned r0 = b0 >> 3, ch0 = (b0 & 7u) ^ (r0 & 7u);
  const unsigned r1 = b1 >> 3, ch1 = (b1 & 7u) ^ (r1 & 7u);

  const char* gK0 = (const char*)Kb + (size_t)(bh * 2048 + r0) * 128 + ch0 * 16;
  const char* gK1 = (const char*)Kb + (size_t)(bh * 2048 + r1) * 128 + ch1 * 16;
  const char* gV0 = (const char*)Vb + (size_t)(bh * 64 + r0) * 4096 + ch0 * 16;
  const char* gV1 = (const char*)Vb + (size_t)(bh * 64 + r1) * 4096 + ch1 * 16;
  const float* bias_base = bias + (size_t)(bh * 2048 + q0 + w * 16 + quad * 4) * 2048 + c;

  async_cp16(gK0, Ks0 + b0 * 16);
  async_cp16(gK1, Ks0 + b1 * 16);
  async_cp16(gV0, Vs0 + b0 * 16);
  async_cp16(gV1, Vs0 + b1 * 16);
  short8 aq[2];
  {
    const u16* qrow = Qb + (size_t)(bh * 2048 + q0 + w * 16 + c) * 64 + quad * 8;
    aq[0] = *(const short8*)(qrow);
    aq[1] = *(const short8*)(qrow + 32);
  }
  float bvA[4][4], bvB[4][4];
#pragma unroll
  for (int tt = 0; tt < 4; ++tt)
#pragma unroll
    for (int r = 0; r < 4; ++r)
      bvA[tt][r] = bias_base[(size_t)r * 2048 + tt * 16] * LOG2E;
  __syncthreads();

  float lsum[4] = {0.f, 0.f, 0.f, 0.f};
  floatx4 oacc[4] = {};

  for (unsigned i = 0; i < 32; ++i) {
    const unsigned k0 = i * 64u;
    const char* Kc = (i & 1u) ? Ks1 : Ks0;
    const char* Vc = (i & 1u) ? Vs1 : Vs0;

    if (i + 1 < 32) {
      char* Kn = (i & 1u) ? Ks0 : Ks1;
      char* Vn = (i & 1u) ? Vs0 : Vs1;
      async_cp16(gK0 + (size_t)(k0 + 64) * 128, Kn + b0 * 16);
      async_cp16(gK1 + (size_t)(k0 + 64) * 128, Kn + b1 * 16);
      async_cp16(gV0 + (size_t)(k0 + 64) * 2, Vn + b0 * 16);
      async_cp16(gV1 + (size_t)(k0 + 64) * 2, Vn + b1 * 16);
#pragma unroll
      for (int tt = 0; tt < 4; ++tt)
#pragma unroll
        for (int r = 0; r < 4; ++r)
          bvB[tt][r] = bias_base[(size_t)r * 2048 + (k0 + 64) + tt * 16] * LOG2E;
    }

    floatx4 s4[4] = {};
    __builtin_amdgcn_s_setprio(1);
#pragma unroll
    for (int ds = 0; ds < 2; ++ds)
#pragma unroll
      for (int tt = 0; tt < 4; ++tt) {
        unsigned row = tt * 16 + c;
        short8 kf = *(const short8*)(Kc + row * 128 + 16 * (((unsigned)quad + 4u * ds) ^ (c & 7u)));
        s4[tt] = __builtin_amdgcn_mfma_f32_16x16x32_bf16(aq[ds], kf, s4[tt], 0, 0, 0);
      }
    __builtin_amdgcn_s_setprio(0);

#pragma unroll
    for (int tt = 0; tt < 4; ++tt)
#pragma unroll
      for (int r = 0; r < 4; ++r)
        s4[tt][r] = __builtin_amdgcn_exp2f(fmaf(s4[tt][r], (LOG2E / 8.0f), bvA[tt][r]));
#pragma unroll
    for (int r = 0; r < 4; ++r)
      lsum[r] += (s4[0][r] + s4[1][r]) + (s4[2][r] + s4[3][r]);

#pragma unroll
    for (int tt = 0; tt < 4; ++tt)
#pragma unroll
      for (int r = 0; r < 4; ++r) {
        unsigned qq = quad * 4 + r;
        unsigned off = pb + qq * 128 + 16 * (((unsigned)(2 * tt) + (c >> 3)) ^ (qq & 7u)) + 2 * (c & 7u);
        *(u16*)(Ps + off) = f2bf(s4[tt][r]);
      }
    asm volatile("s_waitcnt lgkmcnt(0)" ::: "memory");

    __builtin_amdgcn_s_setprio(1);
#pragma unroll
    for (int js = 0; js < 2; ++js) {
      short8 pf = *(const short8*)(Ps + pb + (l & 15) * 128 +
                                   16 * (((unsigned)quad + 4u * js) ^ ((l & 15) & 7u)));
#pragma unroll
      for (int dt = 0; dt < 4; ++dt) {
        unsigned row = dt * 16 + c;
        short8 vf = *(const short8*)(Vc + row * 128 + 16 * (((unsigned)quad + 4u * js) ^ (c & 7u)));
        oacc[dt] = __builtin_amdgcn_mfma_f32_16x16x32_bf16(pf, vf, oacc[dt], 0, 0, 0);
      }
    }
    __builtin_amdgcn_s_setprio(0);

    __syncthreads();

    if (i + 1 < 32) {
#pragma unroll
      for (int tt = 0; tt < 4; ++tt)
#pragma unroll
        for (int r = 0; r < 4; ++r)
          bvA[tt][r] = bvB[tt][r];
    }
  }

#pragma unroll
  for (int r = 0; r < 4; ++r) {
    float rs = lsum[r];
    rs += __shfl_xor(rs, 1);
    rs += __shfl_xor(rs, 2);
    rs += __shfl_xor(rs, 4);
    rs += __shfl_xor(rs, 8);
    lsum[r] = rs;
  }
  unsigned b_ = bh / 12u, h = bh % 12u;
#pragma unroll
  for (int r = 0; r < 4; ++r) {
    float li = 1.0f / lsum[r];
    unsigned qg = q0 + w * 16 + quad * 4 + r;
    float* op = out + (size_t)(b_ * 2048 + qg) * 768 + h * 64 + c;
#pragma unroll
    for (int dt = 0; dt < 4; ++dt) op[dt * 16] = oacc[dt][r] * li;
  }
}

// ------------------------------- probes ------------------------------------
// 128 steps (4 k-sweeps, wrapping). BIAS=1: exact R7 body. BIAS=0: no bias
// loads (constant 0 bias). No global output; keep-alives via asm.
template <int BIAS>
__global__ __launch_bounds__(256, 3) void probe_kernel(
    const u16* __restrict__ Qb, const u16* __restrict__ Kb,
    const u16* __restrict__ Vb, const float* __restrict__ bias) {
  __shared__ __align__(16) char smem[40960];
  char* Ks0 = smem;
  char* Ks1 = smem + 8192;
  char* Vs0 = smem + 16384;
  char* Vs1 = smem + 24576;
  char* Ps  = smem + 32768;
  const unsigned t = threadIdx.x;
  unsigned wgid = (blockIdx.x & 7u) * 96u + (blockIdx.x >> 3);
  const unsigned bh = wgid >> 5, qt = wgid & 31u;
  const unsigned q0 = qt * 64;
  const unsigned w = t >> 6, l = t & 63, quad = l >> 4, c = l & 15;
  const unsigned pb = w * 2048u;

  const unsigned b0 = t, b1 = t + 256u;
  const unsigned r0 = b0 >> 3, ch0 = (b0 & 7u) ^ (r0 & 7u);
  const unsigned r1 = b1 >> 3, ch1 = (b1 & 7u) ^ (r1 & 7u);

  const char* gK0 = (const char*)Kb + (size_t)(bh * 2048 + r0) * 128 + ch0 * 16;
  const char* gK1 = (const char*)Kb + (size_t)(bh * 2048 + r1) * 128 + ch1 * 16;
  const char* gV0 = (const char*)Vb + (size_t)(bh * 64 + r0) * 4096 + ch0 * 16;
  const char* gV1 = (const char*)Vb + (size_t)(bh * 64 + r1) * 4096 + ch1 * 16;
  const float* bias_base = bias + (size_t)(bh * 2048 + q0 + w * 16 + quad * 4) * 2048 + c;

  async_cp16(gK0, Ks0 + b0 * 16);
  async_cp16(gK1, Ks0 + b1 * 16);
  async_cp16(gV0, Vs0 + b0 * 16);
  async_cp16(gV1, Vs0 + b1 * 16);
  short8 aq[2];
  {
    const u16* qrow = Qb + (size_t)(bh * 2048 + q0 + w * 16 + c) * 64 + quad * 8;
    aq[0] = *(const short8*)(qrow);
    aq[1] = *(const short8*)(qrow + 32);
  }
  float bvA[4][4] = {}, bvB[4][4] = {};
  if (BIAS) {
#pragma unroll
    for (int tt = 0; tt < 4; ++tt)
#pragma unroll
      for (int r = 0; r < 4; ++r)
        bvA[tt][r] = bias_base[(size_t)r * 2048 + tt * 16] * LOG2E;
  }
  __syncthreads();

  float lsum[4] = {0.f, 0.f, 0.f, 0.f};
  floatx4 oacc[4] = {};

  for (unsigned i = 0; i < 128; ++i) {
    const char* Kc = (i & 1u) ? Ks1 : Ks0;
    const char* Vc = (i & 1u) ? Vs1 : Vs0;
    const unsigned kn = ((i + 1) & 31u) * 64u;

    if (i + 1 < 128) {
      char* Kn = (i & 1u) ? Ks0 : Ks1;
      char* Vn = (i & 1u) ? Vs0 : Vs1;
      async_cp16(gK0 + (size_t)kn * 128, Kn + b0 * 16);
      async_cp16(gK1 + (size_t)kn * 128, Kn + b1 * 16);
      async_cp16(gV0 + (size_t)kn * 2, Vn + b0 * 16);
      async_cp16(gV1 + (size_t)kn * 2, Vn + b1 * 16);
      if (BIAS) {
#pragma unroll
        for (int tt = 0; tt < 4; ++tt)
#pragma unroll
          for (int r = 0; r < 4; ++r)
            bvB[tt][r] = bias_base[(size_t)r * 2048 + kn + tt * 16] * LOG2E;
      }
    }

    floatx4 s4[4] = {};
    __builtin_amdgcn_s_setprio(1);
#pragma unroll
    for (int ds = 0; ds < 2; ++ds)
#pragma unroll
      for (int tt = 0; tt < 4; ++tt) {
        unsigned row = tt * 16 + c;
        short8 kf = *(const short8*)(Kc + row * 128 + 16 * (((unsigned)quad + 4u * ds) ^ (c & 7u)));
        s4[tt] = __builtin_amdgcn_mfma_f32_16x16x32_bf16(aq[ds], kf, s4[tt], 0, 0, 0);
      }
    __builtin_amdgcn_s_setprio(0);

#pragma unroll
    for (int tt = 0; tt < 4; ++tt)
#pragma unroll
      for (int r = 0; r < 4; ++r)
        s4[tt][r] = __builtin_amdgcn_exp2f(fmaf(s4[tt][r], (LOG2E / 8.0f), bvA[tt][r]));
#pragma unroll
    for (int r = 0; r < 4; ++r)
      lsum[r] += (s4[0][r] + s4[1][r]) + (s4[2][r] + s4[3][r]);

#pragma unroll
    for (int tt = 0; tt < 4; ++tt)
#pragma unroll
      for (int r = 0; r < 4; ++r) {
        unsigned qq = quad * 4 + r;
        unsigned off = pb + qq * 128 + 16 * (((unsigned)(2 * tt) + (c >> 3)) ^ (qq & 7u)) + 2 * (c & 7u);
        *(u16*)(Ps + off) = f2bf(s4[tt][r]);
      }
    asm volatile("s_waitcnt lgkmcnt(0)" ::: "memory");

    __builtin_amdgcn_s_setprio(1);
#pragma unroll
    for (int js = 0; js < 2; ++js) {
      short8 pf = *(const short8*)(Ps + pb + (l & 15) * 128 +
                                   16 * (((unsigned)quad + 4u * js) ^ ((l & 15) & 7u)));
#pragma unroll
      for (int dt = 0; dt < 4; ++dt) {
        unsigned row = dt * 16 + c;
        short8 vf = *(const short8*)(Vc + row * 128 + 16 * (((unsigned)quad + 4u * js) ^ (c & 7u)));
        oacc[dt] = __builtin_amdgcn_mfma_f32_16x16x32_bf16(pf, vf, oacc[dt], 0, 0, 0);
      }
    }
    __builtin_amdgcn_s_setprio(0);

    __syncthreads();

    if (i + 1 < 128 && BIAS) {
#pragma unroll
      for (int tt = 0; tt < 4; ++tt)
#pragma unroll
        for (int r = 0; r < 4; ++r)
          bvA[tt][r] = bvB[tt][r];
    }
  }

  float fsum = 0.f;
#pragma unroll
  for (int r = 0; r < 4; ++r) fsum += lsum[r];
#pragma unroll
  for (int dt = 0; dt < 4; ++dt)
#pragma unroll
    for (int r = 0; r < 4; ++r) fsum += oacc[dt][r];
  asm volatile("" :: "v"(fsum));
}

// ------------------------------- launch ------------------------------------
extern "C" void kernel_launch(void* const* d_in, const int* in_sizes, int n_in,
                              void* d_out, int out_size, void* d_ws, size_t ws_size,
                              hipStream_t stream) {
  const float* hidden = (const float*)d_in[0];   // 4096 x 768
  const float* Wqkv_w = (const float*)d_in[1];   // 2304 x 768
  const float* Wqkv_b = (const float*)d_in[2];   // 2304
  const float* bias   = (const float*)d_in[3];   // 2 x 12 x 2048 x 2048
  float* out = (float*)d_out;

  char* ws = (char*)d_ws;
  u16* Abf = (u16*)(ws);                 //  6,291,456 B
  u16* Wbf = (u16*)(ws + 6291456);       //  3,538,944 B
  u16* Qb  = (u16*)(ws + 9830400);       //  6,291,456 B
  u16* Kb  = (u16*)(ws + 16121856);      //  6,291,456 B
  u16* Vb  = (u16*)(ws + 22413312);      //  6,291,456 B  (total ~27.4 MB)

  pack_kernel<<<4800, 256, 0, stream>>>(hidden, Wqkv_w, Abf, Wbf);
  qkv_gemm<<<dim3(18, 32), 256, 0, stream>>>(Abf, Wbf, Wqkv_b, Qb, Kb, Vb);
  attn_kernel<<<768, 256, 0, stream>>>(Qb, Kb, Vb, bias, out);
  // ---- measurement probes (no output; 128 steps each -> top-5 visible) ----
  probe_kernel<1><<<768, 256, 0, stream>>>(Qb, Kb, Vb, bias);  // PF: full body
  probe_kernel<0><<<768, 256, 0, stream>>>(Qb, Kb, Vb, bias);  // PN: no bias
}